// Round 3
// baseline (499.454 us; speedup 1.0000x reference)
//
#include <hip/hip_runtime.h>
#include <hip/hip_cooperative_groups.h>
#include <math.h>

namespace cg = cooperative_groups;

constexpr int B_   = 8;
constexpr int C_   = 64;
constexpr int H_   = 256;
constexpr int W_   = 256;
constexpr int CR_  = 128;
constexpr int HIN_ = 128;
constexpr int WIN_ = 128;

typedef float f4v __attribute__((ext_vector_type(4)));              // 16B-aligned
typedef float f4u __attribute__((ext_vector_type(4), aligned(4)));  // unaligned vec4

// align_corners=True 2x upsample: pos = j * (HIN-1)/(H-1) = j * 127/255
__device__ __forceinline__ float kScale() { return 127.0f / 255.0f; }

// neighbor selects from a 4-float window; d in {0,1,2}
__device__ __forceinline__ float sel_a(f4u w, int d) {
    return d == 0 ? w[0] : (d == 1 ? w[1] : w[2]);
}
__device__ __forceinline__ float sel_b(f4u w, int d) {
    return d == 0 ? w[1] : (d == 1 ? w[2] : w[3]);
}

// ---------------------------------------------------------------------------
// Cooperative mega-kernel: scores -> grid.sync -> topk -> grid.sync -> fuse.
// Grid = B*CR = 1024 blocks x 256 threads; __launch_bounds__(256,4) caps
// VGPR<=128 so 4 blocks/CU co-residency (1024 = 4*256 CUs) is guaranteed.
// Phase bodies are kept identical to the verified 3-kernel version; the
// structural merge (2 fewer launches, persistent phase-3 blocks) is the
// single variable this round.
// ---------------------------------------------------------------------------
__global__ __launch_bounds__(256, 4) void mega_kernel(
    const float* __restrict__ x, const float* __restrict__ readout,
    const float* __restrict__ weight, const float* __restrict__ bias,
    float* __restrict__ out, float* __restrict__ scores, int* __restrict__ idx)
{
    cg::grid_group grid = cg::this_grid();
    const int t = threadIdx.x;

    // ---------------- Phase 1: scores[b, cr] ----------------
    {
        __shared__ float cw[HIN_];
        __shared__ float red[256];
        const int bc = blockIdx.x;        // b*CR + cr  (grid == B_*CR_)

        if (t < HIN_) {
            float acc = 0.0f;
            const float s = kScale();
            int jlo = 2 * t - 3; if (jlo < 0) jlo = 0;
            int jhi = 2 * t + 3; if (jhi > H_ - 1) jhi = H_ - 1;
            for (int j = jlo; j <= jhi; ++j) {
                float pos = j * s;
                int i0 = (int)pos;                 // pos >= 0: trunc == floor
                if (i0 > HIN_ - 2) i0 = HIN_ - 2;
                float w = pos - (float)i0;
                if (i0 == t)     acc += (1.0f - w);
                if (i0 + 1 == t) acc += w;
            }
            cw[t] = acc * (1.0f / 256.0f);
        }
        __syncthreads();

        const int c4 = t & 31;            // float4 column group
        const int rg = t >> 5;            // 0..7 -> 16 rows each
        const f4v* base = (const f4v*)(readout + (size_t)bc * HIN_ * WIN_);

        f4v a4 = (f4v){0.f, 0.f, 0.f, 0.f};
        const int i0r = rg * 16;
#pragma unroll 4
        for (int i = i0r; i < i0r + 16; ++i) {
            const float cwi = cw[i];
            f4v v = base[i * (WIN_ / 4) + c4];
            a4 += cwi * v;
        }
        red[t] = a4.x * cw[4 * c4 + 0] + a4.y * cw[4 * c4 + 1] +
                 a4.z * cw[4 * c4 + 2] + a4.w * cw[4 * c4 + 3];
        __syncthreads();
        for (int off = 128; off > 0; off >>= 1) {
            if (t < off) red[t] += red[t + off];
            __syncthreads();
        }
        if (t == 0) scores[bc] = red[0];
    }

    grid.sync();

    // ---------------- Phase 2: top-C per batch ----------------
    // Stable descending rank (lowest index wins ties) == jax.lax.top_k.
    if (blockIdx.x < B_) {
        __shared__ float s[CR_];
        const int b = blockIdx.x;
        if (t < CR_) s[t] = scores[b * CR_ + t];
        __syncthreads();
        if (t < CR_) {
            const float mine = s[t];
            int rank = 0;
            for (int o = 0; o < CR_; ++o) {
                float so = s[o];
                rank += (so > mine) || (so == mine && o < t);
            }
            if (rank < C_) idx[b * C_ + rank] = t;
        }
    }

    grid.sync();

    // ---------------- Phase 3: fused upsample + gated blend ----------------
    // 8 consecutive 16-row tiles per block; tile0 = blockIdx*8 spans a single
    // (b,c) (tile>>4 constant over [8m, 8m+7]) so all per-channel and
    // per-lane horizontal state hoists out of the tile loop.
    {
        constexpr int RPB = 16;               // output rows per tile
        const int tile0 = blockIdx.x * 8;
        const int bc    = tile0 >> 4;         // b*C + c   (H/RPB == 16)
        const int hblk0 = tile0 & 15;         // 0 or 8
        const int rgrp  = t >> 6;             // 0..3 (row within group-of-4)
        const int lane  = t & 63;             // float4 index along W
        const int b = bc >> 6;                // C == 64
        const int c = bc & 63;

        const int rc    = idx[b * C_ + c];
        const float w0  = weight[c * 2 + 0];
        const float w1  = weight[c * 2 + 1];
        const float bsv = bias[c];

        const float s = kScale();

        // horizontal neighbor indices/weights for this lane's 4 outputs
        int   j0c[4];
        float wx[4];
        const int wbase = lane * 4;
#pragma unroll
        for (int k = 0; k < 4; ++k) {
            float wpos = (wbase + k) * s;
            int j0 = (int)wpos;
            if (j0 > WIN_ - 2) j0 = WIN_ - 2;
            wx[k]  = wpos - (float)j0;
            j0c[k] = j0;
        }
        int j00 = j0c[0];
        if (j00 > WIN_ - 4) j00 = WIN_ - 4;   // keep [j00..j00+3] in-bounds

        const float* rbase = readout + ((size_t)b * CR_ + rc) * HIN_ * WIN_;

        for (int kt = 0; kt < 8; ++kt) {
            const int hblk = hblk0 + kt;
            const float* xrow0 = x   + (((size_t)bc) * H_ + hblk * RPB + rgrp) * W_;
            float*       orow0 = out + (((size_t)bc) * H_ + hblk * RPB + rgrp) * W_;

#pragma unroll
            for (int rr = 0; rr < 4; ++rr) {
                const int h = hblk * RPB + rr * 4 + rgrp;
                float hpos = h * s;
                int i0 = (int)hpos;           // pos >= 0: trunc == floor
                if (i0 > HIN_ - 2) i0 = HIN_ - 2;
                const float wy = hpos - (float)i0;

                const float* r0 = rbase + (size_t)i0 * WIN_;
                const float* r1 = r0 + WIN_;

                const f4v* xin = (const f4v*)(xrow0 + (size_t)(rr * 4) * W_);
                f4v*       oo  = (f4v*)      (orow0 + (size_t)(rr * 4) * W_);

                const f4v xv  = __builtin_nontemporal_load(&xin[lane]);
                const f4u w0v = *(const f4u*)(r0 + j00);
                const f4u w1v = *(const f4u*)(r1 + j00);

                const float xf[4] = {xv.x, xv.y, xv.z, xv.w};
                f4v ov;
#pragma unroll
                for (int k = 0; k < 4; ++k) {
                    const int d = j0c[k] - j00;   // 0..2
                    float ta = sel_a(w0v, d), tb = sel_b(w0v, d);
                    float ba = sel_a(w1v, d), bb = sel_b(w1v, d);
                    float top = ta + wx[k] * (tb - ta);
                    float bot = ba + wx[k] * (bb - ba);
                    float rv  = top + wy * (bot - top);

                    float z = xf[k] * w0 + rv * w1 + bsv;
                    float g = 1.0f / (1.0f + __expf(-z));
                    ov[k] = xf[k] + g * (rv - xf[k]);
                }
                __builtin_nontemporal_store(ov, &oo[lane]);
            }
        }
    }
}

// ---------------------------------------------------------------------------
// Fallback 3-kernel path (verified at 278.6 us) — used only if the
// cooperative launch is rejected by the runtime.
// ---------------------------------------------------------------------------
__global__ __launch_bounds__(256) void scores_kernel(
    const float* __restrict__ readout, float* __restrict__ scores)
{
    __shared__ float cw[HIN_];
    __shared__ float red[256];
    const int t  = threadIdx.x;
    const int bc = blockIdx.x;

    if (t < HIN_) {
        float acc = 0.0f;
        const float s = kScale();
        int jlo = 2 * t - 3; if (jlo < 0) jlo = 0;
        int jhi = 2 * t + 3; if (jhi > H_ - 1) jhi = H_ - 1;
        for (int j = jlo; j <= jhi; ++j) {
            float pos = j * s;
            int i0 = (int)pos;
            if (i0 > HIN_ - 2) i0 = HIN_ - 2;
            float w = pos - (float)i0;
            if (i0 == t)     acc += (1.0f - w);
            if (i0 + 1 == t) acc += w;
        }
        cw[t] = acc * (1.0f / 256.0f);
    }
    __syncthreads();

    const int c4 = t & 31;
    const int rg = t >> 5;
    const f4v* base = (const f4v*)(readout + (size_t)bc * HIN_ * WIN_);

    f4v a4 = (f4v){0.f, 0.f, 0.f, 0.f};
    const int i0r = rg * 16;
#pragma unroll 4
    for (int i = i0r; i < i0r + 16; ++i) {
        const float cwi = cw[i];
        f4v v = base[i * (WIN_ / 4) + c4];
        a4 += cwi * v;
    }
    red[t] = a4.x * cw[4 * c4 + 0] + a4.y * cw[4 * c4 + 1] +
             a4.z * cw[4 * c4 + 2] + a4.w * cw[4 * c4 + 3];
    __syncthreads();
    for (int off = 128; off > 0; off >>= 1) {
        if (t < off) red[t] += red[t + off];
        __syncthreads();
    }
    if (t == 0) scores[bc] = red[0];
}

__global__ __launch_bounds__(CR_) void topk_kernel(
    const float* __restrict__ scores, int* __restrict__ idx)
{
    __shared__ float s[CR_];
    const int t = threadIdx.x;
    const int b = blockIdx.x;
    s[t] = scores[b * CR_ + t];
    __syncthreads();
    const float mine = s[t];
    int rank = 0;
    for (int o = 0; o < CR_; ++o) {
        float so = s[o];
        rank += (so > mine) || (so == mine && o < t);
    }
    if (rank < C_) idx[b * C_ + rank] = t;
}

__global__ __launch_bounds__(256) void fuse_kernel(
    const float* __restrict__ x, const float* __restrict__ readout,
    const float* __restrict__ weight, const float* __restrict__ bias,
    const int* __restrict__ idx, float* __restrict__ out)
{
    constexpr int RPB = 16;
    const int gid  = blockIdx.x;
    const int bc   = gid >> 4;
    const int hblk = gid & 15;
    const int tid  = threadIdx.x;
    const int rgrp = tid >> 6;
    const int lane = tid & 63;
    const int b = bc >> 6;
    const int c = bc & 63;

    const int rc    = idx[b * C_ + c];
    const float w0  = weight[c * 2 + 0];
    const float w1  = weight[c * 2 + 1];
    const float bsv = bias[c];

    const float s = kScale();

    int   j0c[4];
    float wx[4];
    const int wbase = lane * 4;
#pragma unroll
    for (int k = 0; k < 4; ++k) {
        float wpos = (wbase + k) * s;
        int j0 = (int)wpos;
        if (j0 > WIN_ - 2) j0 = WIN_ - 2;
        wx[k]  = wpos - (float)j0;
        j0c[k] = j0;
    }
    int j00 = j0c[0];
    if (j00 > WIN_ - 4) j00 = WIN_ - 4;

    const float* rbase = readout + ((size_t)b * CR_ + rc) * HIN_ * WIN_;
    const float* xrow0 = x   + (((size_t)bc) * H_ + hblk * RPB + rgrp) * W_;
    float*       orow0 = out + (((size_t)bc) * H_ + hblk * RPB + rgrp) * W_;

#pragma unroll
    for (int rr = 0; rr < 4; ++rr) {
        const int h = hblk * RPB + rr * 4 + rgrp;
        float hpos = h * s;
        int i0 = (int)hpos;
        if (i0 > HIN_ - 2) i0 = HIN_ - 2;
        const float wy = hpos - (float)i0;

        const float* r0 = rbase + (size_t)i0 * WIN_;
        const float* r1 = r0 + WIN_;

        const f4v* xin = (const f4v*)(xrow0 + (size_t)(rr * 4) * W_);
        f4v*       oo  = (f4v*)      (orow0 + (size_t)(rr * 4) * W_);

        const f4v xv  = __builtin_nontemporal_load(&xin[lane]);
        const f4u w0v = *(const f4u*)(r0 + j00);
        const f4u w1v = *(const f4u*)(r1 + j00);

        const float xf[4] = {xv.x, xv.y, xv.z, xv.w};
        f4v ov;
#pragma unroll
        for (int k = 0; k < 4; ++k) {
            const int d = j0c[k] - j00;
            float ta = sel_a(w0v, d), tb = sel_b(w0v, d);
            float ba = sel_a(w1v, d), bb = sel_b(w1v, d);
            float top = ta + wx[k] * (tb - ta);
            float bot = ba + wx[k] * (bb - ba);
            float rv  = top + wy * (bot - top);

            float z = xf[k] * w0 + rv * w1 + bsv;
            float g = 1.0f / (1.0f + __expf(-z));
            ov[k] = xf[k] + g * (rv - xf[k]);
        }
        __builtin_nontemporal_store(ov, &oo[lane]);
    }
}

// ---------------------------------------------------------------------------
extern "C" void kernel_launch(void* const* d_in, const int* in_sizes, int n_in,
                              void* d_out, int out_size, void* d_ws, size_t ws_size,
                              hipStream_t stream)
{
    const float* x       = (const float*)d_in[0];   // [B, C, H, W]
    const float* readout = (const float*)d_in[1];   // [B, CR, HIN, WIN]
    const float* weight  = (const float*)d_in[2];   // [C, 2, 1, 1]
    const float* bias    = (const float*)d_in[3];   // [C]
    float* out = (float*)d_out;                     // [B, C, H, W]

    float* scores = (float*)d_ws;                                   // B*CR floats
    int*   idx    = (int*)((char*)d_ws + B_ * CR_ * sizeof(float)); // B*C ints

    void* args[] = {(void*)&x, (void*)&readout, (void*)&weight, (void*)&bias,
                    (void*)&out, (void*)&scores, (void*)&idx};
    hipError_t err = hipLaunchCooperativeKernel(
        (const void*)mega_kernel, dim3(B_ * CR_), dim3(256), args, 0, stream);
    if (err != hipSuccess) {
        // fallback: verified 3-kernel path
        scores_kernel<<<B_ * CR_, 256, 0, stream>>>(readout, scores);
        topk_kernel<<<B_, CR_, 0, stream>>>(scores, idx);
        fuse_kernel<<<B_ * C_ * (H_ / 16), 256, 0, stream>>>(x, readout, weight, bias, idx, out);
    }
}

// Round 4
// 277.228 us; speedup vs baseline: 1.8016x; 1.8016x over previous
//
#include <hip/hip_runtime.h>
#include <math.h>

constexpr int B_   = 8;
constexpr int C_   = 64;
constexpr int H_   = 256;
constexpr int W_   = 256;
constexpr int CR_  = 128;
constexpr int HIN_ = 128;
constexpr int WIN_ = 128;

typedef float f4v __attribute__((ext_vector_type(4)));              // 16B-aligned
typedef float f4u __attribute__((ext_vector_type(4), aligned(4)));  // unaligned vec4

// align_corners=True 2x upsample: pos = j * (HIN-1)/(H-1) = j * 127/255
__device__ __forceinline__ float kScale() { return 127.0f / 255.0f; }

// ---------------------------------------------------------------------------
// Stage 1: scores[b, cr] = mean over (H, W) of the bilinearly-upsampled
// readout channel = sum_i sum_l cw[i]*cw[l]*r[i][l]  (separable + linear).
// One block per (b, cr); 256 threads; fully-coalesced float4 column loads.
// ---------------------------------------------------------------------------
__global__ __launch_bounds__(256) void scores_kernel(
    const float* __restrict__ readout, float* __restrict__ scores)
{
    __shared__ float cw[HIN_];
    __shared__ float red[256];
    const int t  = threadIdx.x;
    const int bc = blockIdx.x;        // b*CR + cr

    if (t < HIN_) {
        float acc = 0.0f;
        const float s = kScale();
        int jlo = 2 * t - 3; if (jlo < 0) jlo = 0;
        int jhi = 2 * t + 3; if (jhi > H_ - 1) jhi = H_ - 1;
        for (int j = jlo; j <= jhi; ++j) {
            float pos = j * s;
            int i0 = (int)pos;                 // pos >= 0: trunc == floor
            if (i0 > HIN_ - 2) i0 = HIN_ - 2;
            float w = pos - (float)i0;
            if (i0 == t)     acc += (1.0f - w);
            if (i0 + 1 == t) acc += w;
        }
        cw[t] = acc * (1.0f / 256.0f);
    }
    __syncthreads();

    const int c4 = t & 31;            // float4 column group
    const int rg = t >> 5;            // 0..7 -> 16 rows each
    const f4v* base = (const f4v*)(readout + (size_t)bc * HIN_ * WIN_);

    f4v a4 = (f4v){0.f, 0.f, 0.f, 0.f};
    const int i0r = rg * 16;
#pragma unroll 4
    for (int i = i0r; i < i0r + 16; ++i) {
        const float cwi = cw[i];
        f4v v = base[i * (WIN_ / 4) + c4];
        a4 += cwi * v;
    }
    red[t] = a4.x * cw[4 * c4 + 0] + a4.y * cw[4 * c4 + 1] +
             a4.z * cw[4 * c4 + 2] + a4.w * cw[4 * c4 + 3];
    __syncthreads();
    for (int off = 128; off > 0; off >>= 1) {
        if (t < off) red[t] += red[t + off];
        __syncthreads();
    }
    if (t == 0) scores[bc] = red[0];
}

// ---------------------------------------------------------------------------
// Stage 2: top-C indices per batch, descending, stable (lowest index wins
// ties) — matches jax.lax.top_k. One block per batch, CR threads.
// ---------------------------------------------------------------------------
__global__ __launch_bounds__(CR_) void topk_kernel(
    const float* __restrict__ scores, int* __restrict__ idx)
{
    __shared__ float s[CR_];
    const int t = threadIdx.x;
    const int b = blockIdx.x;
    s[t] = scores[b * CR_ + t];
    __syncthreads();
    const float mine = s[t];
    int rank = 0;
    for (int o = 0; o < CR_; ++o) {
        float so = s[o];
        rank += (so > mine) || (so == mine && o < t);
    }
    if (rank < C_) idx[b * C_ + rank] = t;
}

// neighbor selects from a 4-float window; d in {0,1,2}
__device__ __forceinline__ float sel_a(f4u w, int d) {
    return d == 0 ? w[0] : (d == 1 ? w[1] : w[2]);
}
__device__ __forceinline__ float sel_b(f4u w, int d) {
    return d == 0 ? w[1] : (d == 1 ? w[2] : w[3]);
}

// ---------------------------------------------------------------------------
// Stage 3: fused upsample-on-the-fly + sigmoid-gated blend.
// 256 threads cover 16 rows x 64 float4 lanes of one (b,c); grid = 8192.
// (Verified structure @278.6us. Persistent/cooperative variant measured
//  288us standalone at 11% BW, 11% VALU — latency-bound; reverted.)
// Readout loads issued before the nt x load so the longer-latency L3 reads
// start first.
// ---------------------------------------------------------------------------
__global__ __launch_bounds__(256) void fuse_kernel(
    const float* __restrict__ x, const float* __restrict__ readout,
    const float* __restrict__ weight, const float* __restrict__ bias,
    const int* __restrict__ idx, float* __restrict__ out)
{
    constexpr int RPB = 16;                // output rows per block
    const int gid  = blockIdx.x;
    const int bc   = gid >> 4;             // b*C + c   (H/RPB == 16)
    const int hblk = gid & 15;
    const int tid  = threadIdx.x;
    const int rgrp = tid >> 6;             // 0..3 (row within group-of-4)
    const int lane = tid & 63;             // float4 index along W
    const int b = bc >> 6;                 // C == 64
    const int c = bc & 63;

    const int rc    = idx[b * C_ + c];
    const float w0  = weight[c * 2 + 0];
    const float w1  = weight[c * 2 + 1];
    const float bsv = bias[c];

    const float s = kScale();

    // horizontal neighbor indices/weights for this lane's 4 outputs
    // (row-invariant: hoisted out of the row loop)
    int   j0c[4];
    float wx[4];
    const int wbase = lane * 4;
#pragma unroll
    for (int k = 0; k < 4; ++k) {
        float wpos = (wbase + k) * s;
        int j0 = (int)wpos;
        if (j0 > WIN_ - 2) j0 = WIN_ - 2;
        wx[k]  = wpos - (float)j0;
        j0c[k] = j0;
    }
    int j00 = j0c[0];
    if (j00 > WIN_ - 4) j00 = WIN_ - 4;    // keep [j00..j00+3] in-bounds

    const float* rbase = readout + ((size_t)b * CR_ + rc) * HIN_ * WIN_;
    const float* xrow0 = x   + (((size_t)bc) * H_ + hblk * RPB + rgrp) * W_;
    float*       orow0 = out + (((size_t)bc) * H_ + hblk * RPB + rgrp) * W_;

#pragma unroll
    for (int rr = 0; rr < 4; ++rr) {
        const int h = hblk * RPB + rr * 4 + rgrp;
        float hpos = h * s;
        int i0 = (int)hpos;                // pos >= 0: trunc == floor
        if (i0 > HIN_ - 2) i0 = HIN_ - 2;
        const float wy = hpos - (float)i0;

        const float* r0 = rbase + (size_t)i0 * WIN_;
        const float* r1 = r0 + WIN_;

        const f4v* xin = (const f4v*)(xrow0 + (size_t)(rr * 4) * W_);
        f4v*       oo  = (f4v*)      (orow0 + (size_t)(rr * 4) * W_);

        const f4u w0v = *(const f4u*)(r0 + j00);
        const f4u w1v = *(const f4u*)(r1 + j00);
        const f4v xv  = __builtin_nontemporal_load(&xin[lane]);

        const float xf[4] = {xv.x, xv.y, xv.z, xv.w};
        f4v ov;
#pragma unroll
        for (int k = 0; k < 4; ++k) {
            const int d = j0c[k] - j00;    // 0..2
            float ta = sel_a(w0v, d), tb = sel_b(w0v, d);
            float ba = sel_a(w1v, d), bb = sel_b(w1v, d);
            float top = ta + wx[k] * (tb - ta);
            float bot = ba + wx[k] * (bb - ba);
            float rv  = top + wy * (bot - top);

            float z = xf[k] * w0 + rv * w1 + bsv;
            float g = 1.0f / (1.0f + __expf(-z));
            ov[k] = xf[k] + g * (rv - xf[k]);
        }
        __builtin_nontemporal_store(ov, &oo[lane]);
    }
}

// ---------------------------------------------------------------------------
extern "C" void kernel_launch(void* const* d_in, const int* in_sizes, int n_in,
                              void* d_out, int out_size, void* d_ws, size_t ws_size,
                              hipStream_t stream)
{
    const float* x       = (const float*)d_in[0];   // [B, C, H, W]
    const float* readout = (const float*)d_in[1];   // [B, CR, HIN, WIN]
    const float* weight  = (const float*)d_in[2];   // [C, 2, 1, 1]
    const float* bias    = (const float*)d_in[3];   // [C]
    float* out = (float*)d_out;                     // [B, C, H, W]

    float* scores = (float*)d_ws;                                   // B*CR floats
    int*   idx    = (int*)((char*)d_ws + B_ * CR_ * sizeof(float)); // B*C ints

    scores_kernel<<<B_ * CR_, 256, 0, stream>>>(readout, scores);
    topk_kernel<<<B_, CR_, 0, stream>>>(scores, idx);
    fuse_kernel<<<B_ * C_ * (H_ / 16), 256, 0, stream>>>(x, readout, weight, bias, idx, out);
}